// Round 16
// baseline (88.276 us; speedup 1.0000x reference)
//
#include <hip/hip_runtime.h>
#include <hip/hip_bf16.h>

using f32x4 = __attribute__((ext_vector_type(4))) float;
using s16x8 = __attribute__((ext_vector_type(8))) short;   // 8 bf16 (4 VGPRs)

// ---------- bf16 helpers ----------
static __device__ __forceinline__ float bflo2f(unsigned int w) {
    union { unsigned int u; float f; } c; c.u = w << 16; return c.f;
}
static __device__ __forceinline__ float bfhi2f(unsigned int w) {
    union { unsigned int u; float f; } c; c.u = w & 0xffff0000u; return c.f;
}
static __device__ __forceinline__ unsigned int f2bf(float f) {
    union { float f; unsigned int u; } c; c.f = f;
    unsigned int u = c.u;
    u = u + 0x7fffu + ((u >> 16) & 1u);   // round-to-nearest-even
    return u >> 16;
}

#define ET   16    // edges per thread in the bin phase (4096 edges/block)
#define WIN  128   // ints per (bin, block) window; avg fill ~21, Poisson max ~55
#define SPB  4096  // spill ints-pairs per block (== its edge count: worst case)

// ---------- k1: fused convert + wprep + window-bin (NO atomics, NO init) ----
// Block ranges: [0,nxb) x->xb convert | [nxb,nxb+16) weight frags |
// [nxb+16, +nbin) bin. Bin blocks write only block-private regions
// (wincnt row, windows, spill) with plain stores -> no zeroing kernel, no
// global atomics, no ordering hazard with the other ranges.
__global__ __launch_bounds__(256) void k_fused(
        const float* __restrict__ x, unsigned short* __restrict__ xb,
        const float* __restrict__ Wr, const float* __restrict__ Wl,
        s16x8* __restrict__ wprep,
        const int* __restrict__ srcp, const int* __restrict__ dstp,
        int* __restrict__ wincnt, unsigned int* __restrict__ binbuf,
        int* __restrict__ spillcnt, int* __restrict__ spill,
        int E, int n4, int nxb, int nbin, int NB)
{
    int b = blockIdx.x;
    if (b < nxb) {
        int t = b * 256 + threadIdx.x;
        if (t >= n4) return;
        float4 v = ((const float4*)x)[t];
        ushort4 o;
        o.x = (unsigned short)f2bf(v.x);
        o.y = (unsigned short)f2bf(v.y);
        o.z = (unsigned short)f2bf(v.z);
        o.w = (unsigned short)f2bf(v.w);
        ((ushort4*)xb)[t] = o;
    } else if (b < nxb + 16) {
        int s = (b - nxb) * 256 + threadIdx.x;
        if (s >= 4096) return;
        int f = s >> 6, il = s & 63;
        int nt = f >> 3, ks = f & 7;
        int col = nt * 16 + (il & 15);
        int k   = ks * 32 + (il >> 4) * 8;
        const float* Wsrc = (k < 128) ? Wr : Wl;
        int k0 = k & 127;
        const float4* wp = (const float4*)(Wsrc + (size_t)col * 128 + k0);
        float4 w0 = wp[0], w1 = wp[1];
        s16x8 v;
        v[0] = (short)f2bf(w0.x); v[1] = (short)f2bf(w0.y);
        v[2] = (short)f2bf(w0.z); v[3] = (short)f2bf(w0.w);
        v[4] = (short)f2bf(w1.x); v[5] = (short)f2bf(w1.y);
        v[6] = (short)f2bf(w1.z); v[7] = (short)f2bf(w1.w);
        wprep[s] = v;
    } else {
        // ---- bin: LDS histogram -> fixed per-(bin,block) windows ----
        __shared__ int hist[256];
        __shared__ int scnt;
        int bb = b - nxb - 16;
        int t = threadIdx.x;
        hist[t] = 0;
        if (t == 0) scnt = 0;
        __syncthreads();
        int e0 = bb * (256 * ET);
        int binv[ET]; unsigned int pay[ET]; int pls[ET];
        #pragma unroll
        for (int i = 0; i < ET; ++i) {
            int e = e0 + t + i * 256;
            binv[i] = -1;
            if (e < E) {
                int d = dstp[e];
                binv[i] = d >> 8;
                pay[i]  = ((unsigned int)(d & 255) << 24) | (unsigned int)srcp[e];
                pls[i]  = atomicAdd(&hist[binv[i]], 1);
            }
        }
        __syncthreads();
        if (t < NB) wincnt[(size_t)t * nbin + bb] = min(hist[t], WIN);
        #pragma unroll
        for (int i = 0; i < ET; ++i) {
            if (binv[i] >= 0) {
                if (pls[i] < WIN) {
                    binbuf[((size_t)binv[i] * nbin + bb) * WIN + pls[i]] = pay[i];
                } else {                       // ~unreachable for this workload
                    int q = atomicAdd(&scnt, 1);
                    spill[(size_t)bb * 2 * SPB + 2 * q]     = (binv[i] << 8) | (int)(pay[i] >> 24);
                    spill[(size_t)bb * 2 * SPB + 2 * q + 1] = (int)(pay[i] & 0xFFFFFFu);
                }
            }
        }
        __syncthreads();
        if (t == 0) spillcnt[bb] = scnt;
    }
}

// ---------- k2: per-bin node sort from windows -> CSR (srcS, offg, degg) ----
// Thread t owns window (bin b, block t): ~21 entries avg. LDS node histogram
// + scan + placement. Spill regions merged (normally empty).
__global__ __launch_bounds__(256) void k_sort(
        const int* __restrict__ wincnt, const unsigned int* __restrict__ binbuf,
        const int* __restrict__ spillcnt, const int* __restrict__ spill,
        int* __restrict__ srcS, int* __restrict__ offg, int* __restrict__ degg,
        int N, int nbin, int caps)
{
    __shared__ int cnt[256];
    __shared__ int csh[256];
    __shared__ int cur[256];
    int b = blockIdx.x, t = threadIdx.x;
    cnt[t] = 0;
    __syncthreads();
    int myc = 0;
    const unsigned int* wp = nullptr;
    if (t < nbin) {
        myc = wincnt[(size_t)b * nbin + t];
        wp  = binbuf + ((size_t)b * nbin + t) * WIN;
        for (int j = 0; j < myc; ++j) atomicAdd(&cnt[wp[j] >> 24], 1);
        int sc = spillcnt[t];
        for (int j = 0; j < sc; ++j) {
            int d = spill[(size_t)t * 2 * SPB + 2 * j];
            if ((d >> 8) == b) atomicAdd(&cnt[d & 255], 1);
        }
    }
    __syncthreads();
    int v = cnt[t];
    csh[t] = v;
    __syncthreads();
    #pragma unroll
    for (int d2 = 1; d2 < 256; d2 <<= 1) {
        int y = (t >= d2) ? csh[t - d2] : 0;
        __syncthreads();
        csh[t] += y;
        __syncthreads();
    }
    int off = csh[t] - v;                        // exclusive prefix
    cur[t] = off;
    int node = b * 256 + t;
    if (node < N) {
        offg[node] = b * caps + off;
        degg[node] = v;
    }
    __syncthreads();
    if (t < nbin) {
        for (int j = 0; j < myc; ++j) {
            unsigned int p4 = wp[j];
            int p = min(atomicAdd(&cur[p4 >> 24], 1), caps - 1);
            srcS[(size_t)b * caps + p] = (int)(p4 & 0xFFFFFFu);
        }
        int sc = spillcnt[t];
        for (int j = 0; j < sc; ++j) {
            int d = spill[(size_t)t * 2 * SPB + 2 * j];
            if ((d >> 8) == b) {
                int p = min(atomicAdd(&cur[d & 255], 1), caps - 1);
                srcS[(size_t)b * caps + p] = spill[(size_t)t * 2 * SPB + 2 * j + 1];
            }
        }
    }
}

// ---------- k3: wide gather: one wave per dst node, 16 edges in flight ------
__global__ __launch_bounds__(256) void k_gather_wide(
        const uint4* __restrict__ xq, const int* __restrict__ srcS,
        const int* __restrict__ offg, const int* __restrict__ degg,
        uint4* __restrict__ abq, int N)
{
    int d    = blockIdx.x * 4 + (threadIdx.x >> 6);
    int lane = threadIdx.x & 63;
    if (d >= N) return;
    int n0 = offg[d];
    int m0 = degg[d];
    const int* sl = srcS + n0;
    int c = lane & 15, r = lane >> 4;
    float a0=0,a1=0,a2=0,a3=0,a4=0,a5=0,a6=0,a7=0;
    const uint4 z4 = {0u, 0u, 0u, 0u};
    for (int p = 0; p < m0; p += 16) {
        int pe0 = p + r, pe1 = p + 4 + r, pe2 = p + 8 + r, pe3 = p + 12 + r;
        uint4 v0 = z4, v1 = z4, v2 = z4, v3 = z4;
        if (pe0 < m0) v0 = xq[(size_t)sl[pe0] * 16 + c];
        if (pe1 < m0) v1 = xq[(size_t)sl[pe1] * 16 + c];
        if (pe2 < m0) v2 = xq[(size_t)sl[pe2] * 16 + c];
        if (pe3 < m0) v3 = xq[(size_t)sl[pe3] * 16 + c];
        a0 += bflo2f(v0.x); a1 += bfhi2f(v0.x);
        a2 += bflo2f(v0.y); a3 += bfhi2f(v0.y);
        a4 += bflo2f(v0.z); a5 += bfhi2f(v0.z);
        a6 += bflo2f(v0.w); a7 += bfhi2f(v0.w);
        a0 += bflo2f(v1.x); a1 += bfhi2f(v1.x);
        a2 += bflo2f(v1.y); a3 += bfhi2f(v1.y);
        a4 += bflo2f(v1.z); a5 += bfhi2f(v1.z);
        a6 += bflo2f(v1.w); a7 += bfhi2f(v1.w);
        a0 += bflo2f(v2.x); a1 += bfhi2f(v2.x);
        a2 += bflo2f(v2.y); a3 += bfhi2f(v2.y);
        a4 += bflo2f(v2.z); a5 += bfhi2f(v2.z);
        a6 += bflo2f(v2.w); a7 += bfhi2f(v2.w);
        a0 += bflo2f(v3.x); a1 += bfhi2f(v3.x);
        a2 += bflo2f(v3.y); a3 += bfhi2f(v3.y);
        a4 += bflo2f(v3.z); a5 += bfhi2f(v3.z);
        a6 += bflo2f(v3.w); a7 += bfhi2f(v3.w);
    }
    a0 += __shfl_xor(a0, 16, 64); a0 += __shfl_xor(a0, 32, 64);
    a1 += __shfl_xor(a1, 16, 64); a1 += __shfl_xor(a1, 32, 64);
    a2 += __shfl_xor(a2, 16, 64); a2 += __shfl_xor(a2, 32, 64);
    a3 += __shfl_xor(a3, 16, 64); a3 += __shfl_xor(a3, 32, 64);
    a4 += __shfl_xor(a4, 16, 64); a4 += __shfl_xor(a4, 32, 64);
    a5 += __shfl_xor(a5, 16, 64); a5 += __shfl_xor(a5, 32, 64);
    a6 += __shfl_xor(a6, 16, 64); a6 += __shfl_xor(a6, 32, 64);
    a7 += __shfl_xor(a7, 16, 64); a7 += __shfl_xor(a7, 32, 64);
    if (r == 0) {
        float inv = 1.0f / (float)max(m0, 1);
        uint4 o;
        o.x = f2bf(a0 * inv) | (f2bf(a1 * inv) << 16);
        o.y = f2bf(a2 * inv) | (f2bf(a3 * inv) << 16);
        o.z = f2bf(a4 * inv) | (f2bf(a5 * inv) << 16);
        o.w = f2bf(a6 * inv) | (f2bf(a7 * inv) << 16);
        abq[(size_t)d * 16 + c] = o;
    }
}

// ---------- k4: MFMA combine, 128-row tiles (unchanged) ----------
__global__ __launch_bounds__(256) void k_combine_mfma(
        const unsigned short* __restrict__ xb, const unsigned short* __restrict__ ab,
        const s16x8* __restrict__ wprep,
        const float* __restrict__ bl,
        float* __restrict__ out, int N, int T)
{
    __shared__ s16x8 Bf[64][64];                  // 65536 B
    int t = threadIdx.x;
    {
        const uint4* ws = (const uint4*)wprep;
        uint4* bd = (uint4*)&Bf[0][0];
        for (int s = t; s < 4096; s += 256) bd[s] = ws[s];
    }
    __syncthreads();

    int wid = t >> 6, l = t & 63;
    int lr = l & 15, lg = l >> 4;
    float bias[8];
    #pragma unroll
    for (int nt = 0; nt < 8; ++nt) bias[nt] = bl[nt * 16 + lr];

    for (int tile = blockIdx.x; tile < T; tile += gridDim.x) {
        int rb0 = tile * 128 + wid * 32;
        int rb1 = rb0 + 16;
        int ar0 = min(rb0 + lr, N - 1);
        int ar1 = min(rb1 + lr, N - 1);
        const s16x8* xr0 = (const s16x8*)(xb + (size_t)ar0 * 128);
        const s16x8* ag0 = (const s16x8*)(ab + (size_t)ar0 * 128);
        const s16x8* xr1 = (const s16x8*)(xb + (size_t)ar1 * 128);
        const s16x8* ag1 = (const s16x8*)(ab + (size_t)ar1 * 128);
        s16x8 af0[8], af1[8];
        #pragma unroll
        for (int ks = 0; ks < 4; ++ks) {
            af0[ks]     = xr0[ks * 4 + lg];
            af0[4 + ks] = ag0[ks * 4 + lg];
            af1[ks]     = xr1[ks * 4 + lg];
            af1[4 + ks] = ag1[ks * 4 + lg];
        }

        f32x4 acc0[8], acc1[8];
        #pragma unroll
        for (int nt = 0; nt < 8; ++nt) {
            float b = bias[nt];
            acc0[nt] = (f32x4){b, b, b, b};
            acc1[nt] = (f32x4){b, b, b, b};
        }

        #pragma unroll
        for (int ks = 0; ks < 8; ++ks)
            #pragma unroll
            for (int nt = 0; nt < 8; ++nt) {
                s16x8 bfrag = Bf[nt * 8 + ks][l];
                acc0[nt] = __builtin_amdgcn_mfma_f32_16x16x32_bf16(
                               af0[ks], bfrag, acc0[nt], 0, 0, 0);
                acc1[nt] = __builtin_amdgcn_mfma_f32_16x16x32_bf16(
                               af1[ks], bfrag, acc1[nt], 0, 0, 0);
            }

        #pragma unroll
        for (int i = 0; i < 4; ++i) {
            int row0 = rb0 + lg * 4 + i;
            if (row0 < N) {
                float* op = out + (size_t)row0 * 128 + lr;
                #pragma unroll
                for (int nt = 0; nt < 8; ++nt) op[nt * 16] = acc0[nt][i];
            }
            int row1 = rb1 + lg * 4 + i;
            if (row1 < N) {
                float* op = out + (size_t)row1 * 128 + lr;
                #pragma unroll
                for (int nt = 0; nt < 8; ++nt) op[nt * 16] = acc1[nt][i];
            }
        }
    }
}

// ======================= legacy fallback =======================

__global__ __launch_bounds__(256) void k_scatter_legacy(
        const float* __restrict__ x,
        const int* __restrict__ src, const int* __restrict__ dst,
        float* __restrict__ agg, float* __restrict__ deg, int E)
{
    int e    = (int)((blockIdx.x * 256u + threadIdx.x) >> 6);
    int lane = threadIdx.x & 63;
    if (e >= E) return;
    int s = src[e];
    int d = dst[e];
    float2 v = ((const float2*)(x + (size_t)s * 128u))[lane];
    float* ar = agg + (size_t)d * 128u;
    unsafeAtomicAdd(ar + 2 * lane,     v.x);
    unsafeAtomicAdd(ar + 2 * lane + 1, v.y);
    if (lane == 0) unsafeAtomicAdd(deg + d, 1.0f);
}

__global__ __launch_bounds__(256) void k_combine_legacy(
        const float* __restrict__ x, const float* agg, const float* __restrict__ deg,
        const float* __restrict__ Wr, const float* __restrict__ Wl,
        const float* __restrict__ bl,
        float* out, int N)
{
    __shared__ uint4 WT4[64][64];
    for (int idx = threadIdx.x; idx < 64 * 64; idx += 256) {
        int g = idx >> 6, l = idx & 63;
        uint4 wv;
        unsigned int* wp = &wv.x;
        #pragma unroll
        for (int kk = 0; kk < 4; ++kk) {
            int k = g * 4 + kk;
            const float* Wsrc = (k < 128) ? Wr : Wl;
            int km = k & 127;
            unsigned int lo = f2bf(Wsrc[(size_t)l * 128 + km]);
            unsigned int hi = f2bf(Wsrc[(size_t)(l + 64) * 128 + km]);
            wp[kk] = lo | (hi << 16);
        }
        WT4[g][l] = wv;
    }
    __syncthreads();

    int wid = threadIdx.x >> 6, lane = threadIdx.x & 63;
    float b0 = bl[lane], b1 = bl[lane + 64];
    for (int row = blockIdx.x * 4 + wid; row < N; row += gridDim.x * 4) {
        const float4* xr = (const float4*)(x   + (size_t)row * 128);
        const float4* ar = (const float4*)(agg + (size_t)row * 128);
        float inv = 1.0f / fmaxf(deg[row], 1.0f);
        float acc0 = b0, acc1 = b1;
        #pragma unroll 8
        for (int c = 0; c < 32; ++c) {
            uint4 w4 = WT4[c][lane];
            float4 q = xr[c];
            #pragma unroll
            for (int j = 0; j < 4; ++j) {
                unsigned int w = (&w4.x)[j];
                float f = (&q.x)[j];
                acc0 = fmaf(f, bflo2f(w), acc0);
                acc1 = fmaf(f, bfhi2f(w), acc1);
            }
        }
        #pragma unroll 8
        for (int c = 0; c < 32; ++c) {
            uint4 w4 = WT4[c + 32][lane];
            float4 q = ar[c];
            #pragma unroll
            for (int j = 0; j < 4; ++j) {
                unsigned int w = (&w4.x)[j];
                float f = (&q.x)[j] * inv;
                acc0 = fmaf(f, bflo2f(w), acc0);
                acc1 = fmaf(f, bfhi2f(w), acc1);
            }
        }
        out[(size_t)row * 128 + lane]      = acc0;
        out[(size_t)row * 128 + lane + 64] = acc1;
    }
}

// ======================= launch =======================

extern "C" void kernel_launch(void* const* d_in, const int* in_sizes, int n_in,
                              void* d_out, int out_size, void* d_ws, size_t ws_size,
                              hipStream_t stream)
{
    const float* x  = (const float*)d_in[0];
    const int*   ei = (const int*)d_in[1];
    const float* Wl = (const float*)d_in[2];
    const float* bl = (const float*)d_in[3];
    const float* Wr = (const float*)d_in[4];
    float*      out = (float*)d_out;

    int N = in_sizes[0] / 128;
    int E = in_sizes[1] / 2;
    const int* src = ei;          // edge_index[0] = source nodes (j)
    const int* dst = ei + E;      // edge_index[1] = destination nodes (i)

    int NB   = (N + 255) >> 8;                     // 256-node bins
    int nbin = (E + 256 * ET - 1) / (256 * ET);    // bin blocks (4096 edges each)
    int caps = nbin * WIN + SPB;                   // per-bin srcS capacity
    size_t bfB = (size_t)N * 128 * 2;              // bf16 row block

    // ws ints: wincnt[256*nbin] binbuf[NB*nbin*WIN] spillcnt[nbin]
    //          spill[nbin*2*SPB] srcS[NB*caps] offg[N] degg[N]
    size_t nInts = 256 * (size_t)nbin + (size_t)NB * nbin * WIN + nbin
                 + (size_t)nbin * 2 * SPB + (size_t)NB * caps + 2 * (size_t)N;
    size_t intsB = ((nInts * 4) + 255) & ~(size_t)255;

    if (ws_size >= intsB + 2 * bfB + 65536 && NB <= 256 && nbin <= 256
        && N < (1 << 24)) {
        int* wincnt   = (int*)d_ws;
        unsigned int* binbuf = (unsigned int*)(wincnt + 256 * (size_t)nbin);
        int* spillcnt = (int*)(binbuf + (size_t)NB * nbin * WIN);
        int* spill    = spillcnt + nbin;
        int* srcS     = spill + (size_t)nbin * 2 * SPB;
        int* offg     = srcS + (size_t)NB * caps;
        int* degg     = offg + N;
        unsigned short* xb = (unsigned short*)((char*)d_ws + intsB);
        unsigned short* ab = xb + (size_t)N * 128;
        s16x8* wprep = (s16x8*)((char*)ab + bfB);

        int nxb = (N * 32 + 255) / 256;            // convert blocks
        int ntot = nxb + 16 + nbin;                // convert | wprep | bin

        k_fused<<<ntot, 256, 0, stream>>>(x, xb, Wr, Wl, wprep, src, dst,
                                          wincnt, binbuf, spillcnt, spill,
                                          E, N * 32, nxb, nbin, NB);
        k_sort <<<NB, 256, 0, stream>>>(wincnt, binbuf, spillcnt, spill,
                                        srcS, offg, degg, N, nbin, caps);
        k_gather_wide<<<(N + 3) / 4, 256, 0, stream>>>(
                (const uint4*)xb, srcS, offg, degg, (uint4*)ab, N);
        int T = (N + 127) / 128;
        k_combine_mfma<<<T, 256, 0, stream>>>(xb, ab, wprep, bl, out, N, T);
    } else {
        // -------- legacy atomic path (agg = out, deg in ws) --------
        float* agg = out;
        float* deg = (float*)d_ws;
        hipMemsetAsync(out, 0, (size_t)N * 128 * 4, stream);
        hipMemsetAsync(deg, 0, (size_t)N * 4, stream);
        k_scatter_legacy<<<(E + 3) / 4, 256, 0, stream>>>(x, src, dst, agg, deg, E);
        k_combine_legacy<<<1024, 256, 0, stream>>>(x, agg, deg, Wr, Wl, bl, out, N);
    }
}

// Round 17
// 83.541 us; speedup vs baseline: 1.0567x; 1.0567x over previous
//
#include <hip/hip_runtime.h>
#include <hip/hip_bf16.h>

using f32x4 = __attribute__((ext_vector_type(4))) float;
using s16x8 = __attribute__((ext_vector_type(8))) short;   // 8 bf16 (4 VGPRs)

// ---------- bf16 helpers ----------
static __device__ __forceinline__ float bflo2f(unsigned int w) {
    union { unsigned int u; float f; } c; c.u = w << 16; return c.f;
}
static __device__ __forceinline__ float bfhi2f(unsigned int w) {
    union { unsigned int u; float f; } c; c.u = w & 0xffff0000u; return c.f;
}
static __device__ __forceinline__ unsigned int f2bf(float f) {
    union { float f; unsigned int u; } c; c.f = f;
    unsigned int u = c.u;
    u = u + 0x7fffu + ((u >> 16) & 1u);   // round-to-nearest-even
    return u >> 16;
}

#define ET 8     // edges per thread in k_bin

// ---------- k1: convert x->xb + weight fragments + zero bcnt/ovfn ----------
__global__ __launch_bounds__(256) void k_convert(
        const float* __restrict__ x, unsigned short* __restrict__ xb,
        const float* __restrict__ Wr, const float* __restrict__ Wl,
        s16x8* __restrict__ wprep, int* __restrict__ bcnt, int* __restrict__ ovfn,
        int n4, int nxb)
{
    int b = blockIdx.x;
    if (b < nxb) {
        int t = b * 256 + threadIdx.x;
        if (t >= n4) return;
        float4 v = ((const float4*)x)[t];
        ushort4 o;
        o.x = (unsigned short)f2bf(v.x);
        o.y = (unsigned short)f2bf(v.y);
        o.z = (unsigned short)f2bf(v.z);
        o.w = (unsigned short)f2bf(v.w);
        ((ushort4*)xb)[t] = o;
    } else if (b < nxb + 16) {
        int s = (b - nxb) * 256 + threadIdx.x;
        if (s >= 4096) return;
        int f = s >> 6, il = s & 63;
        int nt = f >> 3, ks = f & 7;
        int col = nt * 16 + (il & 15);
        int k   = ks * 32 + (il >> 4) * 8;
        const float* Wsrc = (k < 128) ? Wr : Wl;
        int k0 = k & 127;
        const float4* wp = (const float4*)(Wsrc + (size_t)col * 128 + k0);
        float4 w0 = wp[0], w1 = wp[1];
        s16x8 v;
        v[0] = (short)f2bf(w0.x); v[1] = (short)f2bf(w0.y);
        v[2] = (short)f2bf(w0.z); v[3] = (short)f2bf(w0.w);
        v[4] = (short)f2bf(w1.x); v[5] = (short)f2bf(w1.y);
        v[6] = (short)f2bf(w1.z); v[7] = (short)f2bf(w1.w);
        wprep[s] = v;
    } else {
        int t = threadIdx.x;                     // one block: zero bcnt + ovfn
        bcnt[t] = 0;                             // 256 ints
        if (t == 0) *ovfn = 0;
    }
}

// ---------- k2: coarse-bin edges (dst>>8) into grouped per-bin runs ---------
// LDS histogram per block -> ONE global atomic per (block,bin) to reserve a
// window -> packed 4B payload (d_local<<24 | src) written into grouped runs.
// Replaces 600k random global atomics + 600k random-line stores with
// ~57k global atomics + writes into 196 hot regions. (Round-16's no-atomic
// fixed-window variant regressed: 15MB sparse windows cost more locality
// than the atomics cost serialization.)
__global__ __launch_bounds__(256) void k_bin(
        const int* __restrict__ src, const int* __restrict__ dst,
        int* __restrict__ bcnt, unsigned int* __restrict__ binbuf,
        int* __restrict__ ovfn, int* __restrict__ ovf,
        int E, int NB, int capb)
{
    __shared__ int hist[256];
    __shared__ int base[256];
    int t = threadIdx.x;
    hist[t] = 0;
    __syncthreads();
    int e0 = blockIdx.x * (256 * ET);
    int bins[ET], pls[ET];
    unsigned int pay[ET];
    #pragma unroll
    for (int i = 0; i < ET; ++i) {
        int e = e0 + t + i * 256;
        bins[i] = -1;
        if (e < E) {
            int d = dst[e];
            int s = src[e];
            bins[i] = d >> 8;
            pay[i]  = ((unsigned int)(d & 255) << 24) | (unsigned int)s;
            pls[i]  = atomicAdd(&hist[bins[i]], 1);
        }
    }
    __syncthreads();
    if (t < NB && hist[t] > 0) base[t] = atomicAdd(&bcnt[t], hist[t]);
    __syncthreads();
    #pragma unroll
    for (int i = 0; i < ET; ++i) {
        if (bins[i] >= 0) {
            int pos = base[bins[i]] + pls[i];
            if (pos < capb) {
                binbuf[(size_t)bins[i] * capb + pos] = pay[i];
            } else {                             // ~impossible; any-input safety
                int q = atomicAdd(ovfn, 1);
                ovf[2 * q]     = (bins[i] << 8) | (int)(pay[i] >> 24);
                ovf[2 * q + 1] = (int)(pay[i] & 0xFFFFFFu);
            }
        }
    }
}

// ---------- k3: per-bin LDS counting sort -> CSR (srcS, offg, degg) ---------
__global__ __launch_bounds__(256) void k_sort(
        const int* __restrict__ bcnt, const unsigned int* __restrict__ binbuf,
        int* __restrict__ srcS, int* __restrict__ offg, int* __restrict__ degg,
        int N, int capb)
{
    __shared__ int cnt[256];
    __shared__ int sh[256];
    __shared__ int cur[256];
    int b = blockIdx.x, t = threadIdx.x;
    int m = min(bcnt[b], capb);
    cnt[t] = 0;
    __syncthreads();
    const unsigned int* bb = binbuf + (size_t)b * capb;
    for (int j = t; j < m; j += 256)
        atomicAdd(&cnt[bb[j] >> 24], 1);
    __syncthreads();
    int v = cnt[t];
    sh[t] = v;
    __syncthreads();
    #pragma unroll
    for (int d2 = 1; d2 < 256; d2 <<= 1) {
        int y = (t >= d2) ? sh[t - d2] : 0;
        __syncthreads();
        sh[t] += y;
        __syncthreads();
    }
    int off = sh[t] - v;                         // exclusive prefix
    cur[t] = off;
    int node = b * 256 + t;
    if (node < N) {
        offg[node] = b * capb + off;
        degg[node] = v;
    }
    __syncthreads();
    for (int j = t; j < m; j += 256) {
        unsigned int c = bb[j];
        int p = atomicAdd(&cur[c >> 24], 1);
        srcS[(size_t)b * capb + p] = (int)(c & 0xFFFFFFu);
    }
}

// ---------- k4: wide gather: one wave per dst node, 16 edges in flight ------
// lane = 16*r + c: slot r in [0,4), c in [0,16) = 16B chunk of the row.
__global__ __launch_bounds__(256) void k_gather_wide(
        const uint4* __restrict__ xq, const int* __restrict__ srcS,
        const int* __restrict__ offg, const int* __restrict__ degg,
        const int* __restrict__ ovfn, const int* __restrict__ ovf,
        uint4* __restrict__ abq, int N)
{
    int d    = blockIdx.x * 4 + (threadIdx.x >> 6);
    int lane = threadIdx.x & 63;
    if (d >= N) return;
    int n0 = offg[d];
    int m0 = degg[d];
    const int* sl = srcS + n0;
    int c = lane & 15, r = lane >> 4;
    float a0=0,a1=0,a2=0,a3=0,a4=0,a5=0,a6=0,a7=0;
    const uint4 z4 = {0u, 0u, 0u, 0u};
    for (int p = 0; p < m0; p += 16) {
        int pe0 = p + r, pe1 = p + 4 + r, pe2 = p + 8 + r, pe3 = p + 12 + r;
        uint4 v0 = z4, v1 = z4, v2 = z4, v3 = z4;
        if (pe0 < m0) v0 = xq[(size_t)sl[pe0] * 16 + c];
        if (pe1 < m0) v1 = xq[(size_t)sl[pe1] * 16 + c];
        if (pe2 < m0) v2 = xq[(size_t)sl[pe2] * 16 + c];
        if (pe3 < m0) v3 = xq[(size_t)sl[pe3] * 16 + c];
        a0 += bflo2f(v0.x); a1 += bfhi2f(v0.x);
        a2 += bflo2f(v0.y); a3 += bfhi2f(v0.y);
        a4 += bflo2f(v0.z); a5 += bfhi2f(v0.z);
        a6 += bflo2f(v0.w); a7 += bfhi2f(v0.w);
        a0 += bflo2f(v1.x); a1 += bfhi2f(v1.x);
        a2 += bflo2f(v1.y); a3 += bfhi2f(v1.y);
        a4 += bflo2f(v1.z); a5 += bfhi2f(v1.z);
        a6 += bflo2f(v1.w); a7 += bfhi2f(v1.w);
        a0 += bflo2f(v2.x); a1 += bfhi2f(v2.x);
        a2 += bflo2f(v2.y); a3 += bfhi2f(v2.y);
        a4 += bflo2f(v2.z); a5 += bfhi2f(v2.z);
        a6 += bflo2f(v2.w); a7 += bfhi2f(v2.w);
        a0 += bflo2f(v3.x); a1 += bfhi2f(v3.x);
        a2 += bflo2f(v3.y); a3 += bfhi2f(v3.y);
        a4 += bflo2f(v3.z); a5 += bfhi2f(v3.z);
        a6 += bflo2f(v3.w); a7 += bfhi2f(v3.w);
    }
    int deg = m0;
    int nov = *ovfn;
    for (int k = 0; k < nov; ++k) {              // ~always nov==0
        if (ovf[2 * k] == d) {
            ++deg;
            if (r == 0) {
                uint4 v = xq[(size_t)ovf[2 * k + 1] * 16 + c];
                a0 += bflo2f(v.x); a1 += bfhi2f(v.x);
                a2 += bflo2f(v.y); a3 += bfhi2f(v.y);
                a4 += bflo2f(v.z); a5 += bfhi2f(v.z);
                a6 += bflo2f(v.w); a7 += bfhi2f(v.w);
            }
        }
    }
    a0 += __shfl_xor(a0, 16, 64); a0 += __shfl_xor(a0, 32, 64);
    a1 += __shfl_xor(a1, 16, 64); a1 += __shfl_xor(a1, 32, 64);
    a2 += __shfl_xor(a2, 16, 64); a2 += __shfl_xor(a2, 32, 64);
    a3 += __shfl_xor(a3, 16, 64); a3 += __shfl_xor(a3, 32, 64);
    a4 += __shfl_xor(a4, 16, 64); a4 += __shfl_xor(a4, 32, 64);
    a5 += __shfl_xor(a5, 16, 64); a5 += __shfl_xor(a5, 32, 64);
    a6 += __shfl_xor(a6, 16, 64); a6 += __shfl_xor(a6, 32, 64);
    a7 += __shfl_xor(a7, 16, 64); a7 += __shfl_xor(a7, 32, 64);
    if (r == 0) {
        float inv = 1.0f / (float)max(deg, 1);
        uint4 o;
        o.x = f2bf(a0 * inv) | (f2bf(a1 * inv) << 16);
        o.y = f2bf(a2 * inv) | (f2bf(a3 * inv) << 16);
        o.z = f2bf(a4 * inv) | (f2bf(a5 * inv) << 16);
        o.w = f2bf(a6 * inv) | (f2bf(a7 * inv) << 16);
        abq[(size_t)d * 16 + c] = o;
    }
}

// ---------- k5: MFMA combine, 128-row tiles ----------
__global__ __launch_bounds__(256) void k_combine_mfma(
        const unsigned short* __restrict__ xb, const unsigned short* __restrict__ ab,
        const s16x8* __restrict__ wprep,
        const float* __restrict__ bl,
        float* __restrict__ out, int N, int T)
{
    __shared__ s16x8 Bf[64][64];                  // 65536 B
    int t = threadIdx.x;
    {
        const uint4* ws = (const uint4*)wprep;
        uint4* bd = (uint4*)&Bf[0][0];
        for (int s = t; s < 4096; s += 256) bd[s] = ws[s];
    }
    __syncthreads();

    int wid = t >> 6, l = t & 63;
    int lr = l & 15, lg = l >> 4;
    float bias[8];
    #pragma unroll
    for (int nt = 0; nt < 8; ++nt) bias[nt] = bl[nt * 16 + lr];

    for (int tile = blockIdx.x; tile < T; tile += gridDim.x) {
        int rb0 = tile * 128 + wid * 32;
        int rb1 = rb0 + 16;
        int ar0 = min(rb0 + lr, N - 1);
        int ar1 = min(rb1 + lr, N - 1);
        const s16x8* xr0 = (const s16x8*)(xb + (size_t)ar0 * 128);
        const s16x8* ag0 = (const s16x8*)(ab + (size_t)ar0 * 128);
        const s16x8* xr1 = (const s16x8*)(xb + (size_t)ar1 * 128);
        const s16x8* ag1 = (const s16x8*)(ab + (size_t)ar1 * 128);
        s16x8 af0[8], af1[8];
        #pragma unroll
        for (int ks = 0; ks < 4; ++ks) {
            af0[ks]     = xr0[ks * 4 + lg];
            af0[4 + ks] = ag0[ks * 4 + lg];
            af1[ks]     = xr1[ks * 4 + lg];
            af1[4 + ks] = ag1[ks * 4 + lg];
        }

        f32x4 acc0[8], acc1[8];
        #pragma unroll
        for (int nt = 0; nt < 8; ++nt) {
            float b = bias[nt];
            acc0[nt] = (f32x4){b, b, b, b};
            acc1[nt] = (f32x4){b, b, b, b};
        }

        #pragma unroll
        for (int ks = 0; ks < 8; ++ks)
            #pragma unroll
            for (int nt = 0; nt < 8; ++nt) {
                s16x8 bfrag = Bf[nt * 8 + ks][l];
                acc0[nt] = __builtin_amdgcn_mfma_f32_16x16x32_bf16(
                               af0[ks], bfrag, acc0[nt], 0, 0, 0);
                acc1[nt] = __builtin_amdgcn_mfma_f32_16x16x32_bf16(
                               af1[ks], bfrag, acc1[nt], 0, 0, 0);
            }

        #pragma unroll
        for (int i = 0; i < 4; ++i) {
            int row0 = rb0 + lg * 4 + i;
            if (row0 < N) {
                float* op = out + (size_t)row0 * 128 + lr;
                #pragma unroll
                for (int nt = 0; nt < 8; ++nt) op[nt * 16] = acc0[nt][i];
            }
            int row1 = rb1 + lg * 4 + i;
            if (row1 < N) {
                float* op = out + (size_t)row1 * 128 + lr;
                #pragma unroll
                for (int nt = 0; nt < 8; ++nt) op[nt * 16] = acc1[nt][i];
            }
        }
    }
}

// ======================= legacy fallback =======================

__global__ __launch_bounds__(256) void k_scatter_legacy(
        const float* __restrict__ x,
        const int* __restrict__ src, const int* __restrict__ dst,
        float* __restrict__ agg, float* __restrict__ deg, int E)
{
    int e    = (int)((blockIdx.x * 256u + threadIdx.x) >> 6);
    int lane = threadIdx.x & 63;
    if (e >= E) return;
    int s = src[e];
    int d = dst[e];
    float2 v = ((const float2*)(x + (size_t)s * 128u))[lane];
    float* ar = agg + (size_t)d * 128u;
    unsafeAtomicAdd(ar + 2 * lane,     v.x);
    unsafeAtomicAdd(ar + 2 * lane + 1, v.y);
    if (lane == 0) unsafeAtomicAdd(deg + d, 1.0f);
}

__global__ __launch_bounds__(256) void k_combine_legacy(
        const float* __restrict__ x, const float* agg, const float* __restrict__ deg,
        const float* __restrict__ Wr, const float* __restrict__ Wl,
        const float* __restrict__ bl,
        float* out, int N)
{
    __shared__ uint4 WT4[64][64];
    for (int idx = threadIdx.x; idx < 64 * 64; idx += 256) {
        int g = idx >> 6, l = idx & 63;
        uint4 wv;
        unsigned int* wp = &wv.x;
        #pragma unroll
        for (int kk = 0; kk < 4; ++kk) {
            int k = g * 4 + kk;
            const float* Wsrc = (k < 128) ? Wr : Wl;
            int km = k & 127;
            unsigned int lo = f2bf(Wsrc[(size_t)l * 128 + km]);
            unsigned int hi = f2bf(Wsrc[(size_t)(l + 64) * 128 + km]);
            wp[kk] = lo | (hi << 16);
        }
        WT4[g][l] = wv;
    }
    __syncthreads();

    int wid = threadIdx.x >> 6, lane = threadIdx.x & 63;
    float b0 = bl[lane], b1 = bl[lane + 64];
    for (int row = blockIdx.x * 4 + wid; row < N; row += gridDim.x * 4) {
        const float4* xr = (const float4*)(x   + (size_t)row * 128);
        const float4* ar = (const float4*)(agg + (size_t)row * 128);
        float inv = 1.0f / fmaxf(deg[row], 1.0f);
        float acc0 = b0, acc1 = b1;
        #pragma unroll 8
        for (int c = 0; c < 32; ++c) {
            uint4 w4 = WT4[c][lane];
            float4 q = xr[c];
            #pragma unroll
            for (int j = 0; j < 4; ++j) {
                unsigned int w = (&w4.x)[j];
                float f = (&q.x)[j];
                acc0 = fmaf(f, bflo2f(w), acc0);
                acc1 = fmaf(f, bfhi2f(w), acc1);
            }
        }
        #pragma unroll 8
        for (int c = 0; c < 32; ++c) {
            uint4 w4 = WT4[c + 32][lane];
            float4 q = ar[c];
            #pragma unroll
            for (int j = 0; j < 4; ++j) {
                unsigned int w = (&w4.x)[j];
                float f = (&q.x)[j] * inv;
                acc0 = fmaf(f, bflo2f(w), acc0);
                acc1 = fmaf(f, bfhi2f(w), acc1);
            }
        }
        out[(size_t)row * 128 + lane]      = acc0;
        out[(size_t)row * 128 + lane + 64] = acc1;
    }
}

// ======================= launch =======================

extern "C" void kernel_launch(void* const* d_in, const int* in_sizes, int n_in,
                              void* d_out, int out_size, void* d_ws, size_t ws_size,
                              hipStream_t stream)
{
    const float* x  = (const float*)d_in[0];
    const int*   ei = (const int*)d_in[1];
    const float* Wl = (const float*)d_in[2];
    const float* bl = (const float*)d_in[3];
    const float* Wr = (const float*)d_in[4];
    float*      out = (float*)d_out;

    int N = in_sizes[0] / 128;
    int E = in_sizes[1] / 2;
    const int* src = ei;          // edge_index[0] = source nodes (j)
    const int* dst = ei + E;      // edge_index[1] = destination nodes (i)

    int NB   = (N + 255) >> 8;                         // 256-node bins
    int capb = ((2 * E / (NB > 0 ? NB : 1)) + 255) & ~255;   // per-bin capacity
    size_t bfB = (size_t)N * 128 * 2;                  // bf16 row block

    // ws: bcnt[256] ovfn[64] ovf[2E] binbuf[NB*capb] srcS[NB*capb]
    //     offg[N] degg[N] | xb | ab | wprep(64KB)
    size_t nInts = 256 + 64 + 2 * (size_t)E + 2 * (size_t)NB * capb
                 + 2 * (size_t)N;
    size_t intsB = ((nInts * 4) + 255) & ~(size_t)255;

    if (ws_size >= intsB + 2 * bfB + 65536 && NB <= 256 && N < (1 << 24)) {
        int* bcnt = (int*)d_ws;
        int* ovfn = bcnt + 256;
        int* ovf  = ovfn + 64;
        unsigned int* binbuf = (unsigned int*)(ovf + 2 * (size_t)E);
        int* srcS = (int*)(binbuf + (size_t)NB * capb);
        int* offg = srcS + (size_t)NB * capb;
        int* degg = offg + N;
        unsigned short* xb = (unsigned short*)((char*)d_ws + intsB);
        unsigned short* ab = xb + (size_t)N * 128;
        s16x8* wprep = (s16x8*)((char*)ab + bfB);

        int nxb = (N * 32 + 255) / 256;                // convert blocks
        int ncv = nxb + 16 + 1;                        // convert | wprep | zero
        int nbin = (E + 256 * ET - 1) / (256 * ET);    // bin blocks

        k_convert<<<ncv, 256, 0, stream>>>(x, xb, Wr, Wl, wprep, bcnt, ovfn,
                                           N * 32, nxb);
        k_bin    <<<nbin, 256, 0, stream>>>(src, dst, bcnt, binbuf, ovfn, ovf,
                                            E, NB, capb);
        k_sort   <<<NB, 256, 0, stream>>>(bcnt, binbuf, srcS, offg, degg,
                                          N, capb);
        k_gather_wide<<<(N + 3) / 4, 256, 0, stream>>>(
                (const uint4*)xb, srcS, offg, degg, ovfn, ovf, (uint4*)ab, N);
        int T = (N + 127) / 128;
        k_combine_mfma<<<T, 256, 0, stream>>>(xb, ab, wprep, bl, out, N, T);
    } else {
        // -------- legacy atomic path (agg = out, deg in ws) --------
        float* agg = out;
        float* deg = (float*)d_ws;
        hipMemsetAsync(out, 0, (size_t)N * 128 * 4, stream);
        hipMemsetAsync(deg, 0, (size_t)N * 4, stream);
        k_scatter_legacy<<<(E + 3) / 4, 256, 0, stream>>>(x, src, dst, agg, deg, E);
        k_combine_legacy<<<1024, 256, 0, stream>>>(x, agg, deg, Wr, Wl, bl, out, N);
    }
}